// Round 1
// baseline (12787.380 us; speedup 1.0000x reference)
//
#include <hip/hip_runtime.h>

#define N0 16384
#define N1 4096
#define N2 1024
#define E0C 131072
#define FIN 384
#define HF 512

// ---------------- helpers ----------------
__device__ inline float4 f4fma(float w, const float4 v, float4 a) {
  a.x = fmaf(w, v.x, a.x); a.y = fmaf(w, v.y, a.y);
  a.z = fmaf(w, v.z, a.z); a.w = fmaf(w, v.w, a.w);
  return a;
}

// ---------------- CSR build for level-0 random graph ----------------
__global__ __launch_bounds__(256)
void count_deg(const int* __restrict__ dst, int* __restrict__ cnt, int E) {
  int e = blockIdx.x * 256 + threadIdx.x;
  if (e < E) atomicAdd(&cnt[dst[e]], 1);
}

__global__ __launch_bounds__(1024)
void scan_offsets(const int* __restrict__ cnt, int* __restrict__ offs,
                  float* __restrict__ dinv) {
  // n = 16384 fixed: 1024 threads x 16
  __shared__ int ts[1024];
  const int t = threadIdx.x;
  int local[16];
  int sum = 0;
  #pragma unroll
  for (int j = 0; j < 16; ++j) { local[j] = cnt[t * 16 + j]; sum += local[j]; }
  ts[t] = sum;
  __syncthreads();
  for (int off = 1; off < 1024; off <<= 1) {
    int v = (t >= off) ? ts[t - off] : 0;
    __syncthreads();
    ts[t] += v;
    __syncthreads();
  }
  int run = ts[t] - sum;  // exclusive prefix
  #pragma unroll
  for (int j = 0; j < 16; ++j) {
    offs[t * 16 + j] = run;
    dinv[t * 16 + j] = 1.0f / sqrtf((float)local[j] + 2.0f);
    run += local[j];
  }
  if (t == 1023) offs[N0] = run;
}

__global__ __launch_bounds__(256)
void fill_csr(const int* __restrict__ src, const int* __restrict__ dst,
              const int* __restrict__ offs, int* __restrict__ cursor,
              int* __restrict__ srcl, int E) {
  int e = blockIdx.x * 256 + threadIdx.x;
  if (e < E) {
    int d = dst[e];
    int p = atomicAdd(&cursor[d], 1);
    srcl[offs[d] + p] = src[e];
  }
}

// ---------------- fp32 GEMM: C[M,N] = A[M,K] @ W[K,N] (+bias) ----------------
template<int BM, int BN, int BK>
__global__ __launch_bounds__(256)
void gemm_f32(const float* __restrict__ A, const float* __restrict__ W,
              const float* __restrict__ bias, float* __restrict__ C,
              int M, int N, int K, int addBias) {
  __shared__ float As[BK][BM + 4];  // stride 132 floats = 16B aligned rows
  __shared__ float Ws[BK][BN];
  const int tid = threadIdx.x;
  const int bm = blockIdx.x * BM;
  const int bn = blockIdx.y * BN;
  const int tx = tid & 15;
  const int ty = tid >> 4;
  float acc[8][4];
  #pragma unroll
  for (int i = 0; i < 8; ++i)
    #pragma unroll
    for (int j = 0; j < 4; ++j) acc[i][j] = 0.f;

  for (int k0 = 0; k0 < K; k0 += BK) {
    #pragma unroll
    for (int h = 0; h < (BM * BK) / (256 * 4); ++h) {
      int q = tid + h * 256;
      int r = q >> 2;
      int c = (q & 3) << 2;
      float4 v = *(const float4*)(A + (size_t)(bm + r) * K + k0 + c);
      As[c][r] = v.x; As[c + 1][r] = v.y; As[c + 2][r] = v.z; As[c + 3][r] = v.w;
    }
    {
      int kk = tid >> 4;
      int n = (tid & 15) << 2;
      *(float4*)(&Ws[kk][n]) = *(const float4*)(W + (size_t)(k0 + kk) * N + bn + n);
    }
    __syncthreads();
    #pragma unroll
    for (int kk = 0; kk < BK; ++kk) {
      float4 b4 = *(const float4*)(&Ws[kk][tx << 2]);
      float4 a0 = *(const float4*)(&As[kk][ty << 3]);
      float4 a1 = *(const float4*)(&As[kk][(ty << 3) + 4]);
      float a[8] = {a0.x, a0.y, a0.z, a0.w, a1.x, a1.y, a1.z, a1.w};
      float b[4] = {b4.x, b4.y, b4.z, b4.w};
      #pragma unroll
      for (int i = 0; i < 8; ++i)
        #pragma unroll
        for (int j = 0; j < 4; ++j)
          acc[i][j] = fmaf(a[i], b[j], acc[i][j]);
    }
    __syncthreads();
  }
  #pragma unroll
  for (int i = 0; i < 8; ++i) {
    int row = bm + (ty << 3) + i;
    float4 o = {acc[i][0], acc[i][1], acc[i][2], acc[i][3]};
    if (addBias) {
      const float4 bb = *(const float4*)(bias + bn + (tx << 2));
      o.x += bb.x; o.y += bb.y; o.z += bb.z; o.w += bb.w;
    }
    *(float4*)(C + (size_t)row * N + bn + (tx << 2)) = o;
  }
}

// ---------------- GCN aggregation (CSR, level-0 random graph) ----------------
__global__ __launch_bounds__(256)
void gcn_agg_csr(const float* __restrict__ h, const int* __restrict__ offs,
                 const int* __restrict__ srcl, const float* __restrict__ dinv,
                 const float* __restrict__ bias, float* __restrict__ out, int n) {
  const int wid = threadIdx.x >> 6, lane = threadIdx.x & 63;
  const int node = blockIdx.x * 4 + wid;
  if (node >= n) return;
  const float di = dinv[node];
  const int s0 = offs[node], s1 = offs[node + 1];
  float4 a0 = {0, 0, 0, 0}, a1 = {0, 0, 0, 0};
  for (int e = s0; e < s1; ++e) {
    const int s = srcl[e];
    const float w = dinv[s] * di;
    const float4* r = (const float4*)(h + (size_t)s * HF);
    a0 = f4fma(w, r[lane], a0);
    a1 = f4fma(w, r[64 + lane], a1);
  }
  const float sw = 2.0f * di * di;
  const float4* rs = (const float4*)(h + (size_t)node * HF);
  a0 = f4fma(sw, rs[lane], a0);
  a1 = f4fma(sw, rs[64 + lane], a1);
  const float4 b0 = *(const float4*)(bias + (lane << 2));
  const float4 b1 = *(const float4*)(bias + 256 + (lane << 2));
  a0.x = fmaxf(a0.x + b0.x, 0.f); a0.y = fmaxf(a0.y + b0.y, 0.f);
  a0.z = fmaxf(a0.z + b0.z, 0.f); a0.w = fmaxf(a0.w + b0.w, 0.f);
  a1.x = fmaxf(a1.x + b1.x, 0.f); a1.y = fmaxf(a1.y + b1.y, 0.f);
  a1.z = fmaxf(a1.z + b1.z, 0.f); a1.w = fmaxf(a1.w + b1.w, 0.f);
  float4* o = (float4*)(out + (size_t)node * HF);
  o[lane] = a0; o[64 + lane] = a1;
}

// ---------------- GCN aggregation (implicit-CSR kNN graph) ----------------
template<int K>
__global__ __launch_bounds__(256)
void gcn_agg_knn(const float* __restrict__ h, const int* __restrict__ nbr,
                 const float* __restrict__ bias, float* __restrict__ out, int n) {
  const int wid = threadIdx.x >> 6, lane = threadIdx.x & 63;
  const int node = blockIdx.x * 4 + wid;
  if (node >= n) return;
  const float di = 1.0f / sqrtf((float)(K + 2));
  const float w = di * di;
  float4 a0 = {0, 0, 0, 0}, a1 = {0, 0, 0, 0};
  #pragma unroll
  for (int j = 0; j < K; ++j) {
    const int s = nbr[node * K + j];
    const float4* r = (const float4*)(h + (size_t)s * HF);
    a0 = f4fma(w, r[lane], a0);
    a1 = f4fma(w, r[64 + lane], a1);
  }
  const float sw = 2.0f * di * di;
  const float4* rs = (const float4*)(h + (size_t)node * HF);
  a0 = f4fma(sw, rs[lane], a0);
  a1 = f4fma(sw, rs[64 + lane], a1);
  const float4 b0 = *(const float4*)(bias + (lane << 2));
  const float4 b1 = *(const float4*)(bias + 256 + (lane << 2));
  a0.x = fmaxf(a0.x + b0.x, 0.f); a0.y = fmaxf(a0.y + b0.y, 0.f);
  a0.z = fmaxf(a0.z + b0.z, 0.f); a0.w = fmaxf(a0.w + b0.w, 0.f);
  a1.x = fmaxf(a1.x + b1.x, 0.f); a1.y = fmaxf(a1.y + b1.y, 0.f);
  a1.z = fmaxf(a1.z + b1.z, 0.f); a1.w = fmaxf(a1.w + b1.w, 0.f);
  float4* o = (float4*)(out + (size_t)node * HF);
  o[lane] = a0; o[64 + lane] = a1;
}

// ---------------- FPS (exact reference replication) ----------------
template<int N, int PPT, int NKEEP>
__global__ __launch_bounds__(1024)
void fps_kernel(const float* __restrict__ pos, int* __restrict__ perm,
                float* __restrict__ pos_out) {
  const int t = threadIdx.x;
  const int lane = t & 63, wid = t >> 6;
  float px[PPT], py[PPT], dist[PPT];
  const int base = t * PPT;
  #pragma unroll
  for (int j = 0; j < PPT; ++j) {
    px[j] = pos[2 * (base + j)];
    py[j] = pos[2 * (base + j) + 1];
    dist[j] = 3.4e38f;
  }
  float cx = pos[0], cy = pos[1];
  if (t == 0) { perm[0] = 0; pos_out[0] = cx; pos_out[1] = cy; }
  __shared__ float rv[16], rx[16], ry[16];
  __shared__ int ri[16];
  __shared__ float bcx, bcy;
  for (int i = 1; i < NKEEP; ++i) {
    // fused: min-update with (cx,cy) + local argmax (first-index ties)
    float lv = -1.f, lx = 0.f, ly = 0.f;
    int li = 0x7fffffff;
    #pragma unroll
    for (int j = 0; j < PPT; ++j) {
      float dx = __fsub_rn(px[j], cx), dy = __fsub_rn(py[j], cy);
      float nd = __fadd_rn(__fmul_rn(dx, dx), __fmul_rn(dy, dy));
      float d = fminf(dist[j], nd);
      dist[j] = d;
      if (d > lv) { lv = d; li = base + j; lx = px[j]; ly = py[j]; }
    }
    // wave reduce (tie: smaller index wins)
    #pragma unroll
    for (int m = 1; m < 64; m <<= 1) {
      float ov = __shfl_xor(lv, m); int oi = __shfl_xor(li, m);
      float ox = __shfl_xor(lx, m); float oy = __shfl_xor(ly, m);
      if (ov > lv || (ov == lv && oi < li)) { lv = ov; li = oi; lx = ox; ly = oy; }
    }
    if (lane == 0) { rv[wid] = lv; ri[wid] = li; rx[wid] = lx; ry[wid] = ly; }
    __syncthreads();
    if (t < 16) {
      lv = rv[t]; li = ri[t]; lx = rx[t]; ly = ry[t];
      #pragma unroll
      for (int m = 1; m < 16; m <<= 1) {
        float ov = __shfl_xor(lv, m); int oi = __shfl_xor(li, m);
        float ox = __shfl_xor(lx, m); float oy = __shfl_xor(ly, m);
        if (ov > lv || (ov == lv && oi < li)) { lv = ov; li = oi; lx = ox; ly = oy; }
      }
      if (t == 0) {
        perm[i] = li; pos_out[2 * i] = lx; pos_out[2 * i + 1] = ly;
        bcx = lx; bcy = ly;
      }
    }
    __syncthreads();
    cx = bcx; cy = bcy;
  }
}

// ---------------- row gather ----------------
__global__ __launch_bounds__(256)
void gather_rows(const float* __restrict__ xin, const int* __restrict__ perm,
                 float* __restrict__ xout, int n) {
  const int wid = threadIdx.x >> 6, lane = threadIdx.x & 63;
  const int i = blockIdx.x * 4 + wid;
  if (i >= n) return;
  const int s = perm[i];
  const float4* r = (const float4*)(xin + (size_t)s * HF);
  float4* o = (float4*)(xout + (size_t)i * HF);
  o[lane] = r[lane];
  o[64 + lane] = r[64 + lane];
}

// ---------------- kNN graph (self-excluded), exact pdist2 replication ----------------
template<int NPTS, int K>
__global__ __launch_bounds__(256)
void knn_graph_kernel(const float* __restrict__ pos, int* __restrict__ srcout) {
  __shared__ float sx[NPTS], sy[NPTS], ss[NPTS];
  const int tid = threadIdx.x;
  for (int idx = tid; idx < NPTS; idx += 256) {
    float x = pos[2 * idx], y = pos[2 * idx + 1];
    sx[idx] = x; sy[idx] = y;
    ss[idx] = __fadd_rn(__fmul_rn(x, x), __fmul_rn(y, y));
  }
  __syncthreads();
  const int q = blockIdx.x * 256 + tid;
  const float qx = sx[q], qy = sy[q], qs = ss[q];
  float bd[K]; int bi[K];
  #pragma unroll
  for (int m = 0; m < K; ++m) { bd[m] = 3.4e38f; bi[m] = 0; }
  for (int j = 0; j < NPTS; ++j) {
    if (j == q) continue;
    float dot = __fadd_rn(__fmul_rn(qx, sx[j]), __fmul_rn(qy, sy[j]));
    float d2 = fmaxf(__fsub_rn(__fadd_rn(qs, ss[j]), __fmul_rn(2.0f, dot)), 0.0f);
    if (d2 < bd[K - 1]) {
      bool pr[K];
      #pragma unroll
      for (int m = 0; m < K; ++m) pr[m] = (d2 < bd[m]);
      #pragma unroll
      for (int m = K - 1; m >= 1; --m) {
        bd[m] = pr[m] ? (pr[m - 1] ? bd[m - 1] : d2) : bd[m];
        bi[m] = pr[m] ? (pr[m - 1] ? bi[m - 1] : j) : bi[m];
      }
      if (pr[0]) { bd[0] = d2; bi[0] = j; }
    }
  }
  #pragma unroll
  for (int m = 0; m < K; ++m) srcout[q * K + m] = bi[m];
}

// ---------------- kNN interpolate: top-k + weights ----------------
template<int NX, int K>
__global__ __launch_bounds__(256)
void interp_topk(const float* __restrict__ posy, const float* __restrict__ posx,
                 int* __restrict__ oidx, float* __restrict__ ow,
                 float* __restrict__ owsum) {
  __shared__ float sx[NX], sy[NX], ss[NX];
  const int tid = threadIdx.x;
  for (int idx = tid; idx < NX; idx += 256) {
    float x = posx[2 * idx], y = posx[2 * idx + 1];
    sx[idx] = x; sy[idx] = y;
    ss[idx] = __fadd_rn(__fmul_rn(x, x), __fmul_rn(y, y));
  }
  __syncthreads();
  const int q = blockIdx.x * 256 + tid;
  const float qx = posy[2 * q], qy = posy[2 * q + 1];
  const float qs = __fadd_rn(__fmul_rn(qx, qx), __fmul_rn(qy, qy));
  float bd[K]; int bi[K];
  #pragma unroll
  for (int m = 0; m < K; ++m) { bd[m] = 3.4e38f; bi[m] = 0; }
  for (int j = 0; j < NX; ++j) {
    float dot = __fadd_rn(__fmul_rn(qx, sx[j]), __fmul_rn(qy, sy[j]));
    float d2 = fmaxf(__fsub_rn(__fadd_rn(qs, ss[j]), __fmul_rn(2.0f, dot)), 0.0f);
    if (d2 < bd[K - 1]) {
      bool pr[K];
      #pragma unroll
      for (int m = 0; m < K; ++m) pr[m] = (d2 < bd[m]);
      #pragma unroll
      for (int m = K - 1; m >= 1; --m) {
        bd[m] = pr[m] ? (pr[m - 1] ? bd[m - 1] : d2) : bd[m];
        bi[m] = pr[m] ? (pr[m - 1] ? bi[m - 1] : j) : bi[m];
      }
      if (pr[0]) { bd[0] = d2; bi[0] = j; }
    }
  }
  float wsum = 0.f;
  #pragma unroll
  for (int m = 0; m < K; ++m) {
    float w = 1.0f / fmaxf(bd[m], 1e-16f);
    ow[q * K + m] = w;
    oidx[q * K + m] = bi[m];
    wsum = __fadd_rn(wsum, w);
  }
  owsum[q] = wsum;
}

template<int K>
__global__ __launch_bounds__(256)
void interp_combine(const float* __restrict__ xin, const int* __restrict__ idx,
                    const float* __restrict__ w, const float* __restrict__ wsum,
                    float* __restrict__ out, int ny) {
  const int wid = threadIdx.x >> 6, lane = threadIdx.x & 63;
  const int q = blockIdx.x * 4 + wid;
  if (q >= ny) return;
  float4 a0 = {0, 0, 0, 0}, a1 = {0, 0, 0, 0};
  #pragma unroll
  for (int m = 0; m < K; ++m) {
    const int s = idx[q * K + m];
    const float wk = w[q * K + m];
    const float4* r = (const float4*)(xin + (size_t)s * HF);
    a0 = f4fma(wk, r[lane], a0);
    a1 = f4fma(wk, r[64 + lane], a1);
  }
  const float inv = wsum[q];
  a0.x /= inv; a0.y /= inv; a0.z /= inv; a0.w /= inv;
  a1.x /= inv; a1.y /= inv; a1.z /= inv; a1.w /= inv;
  float4* o = (float4*)(out + (size_t)q * HF);
  o[lane] = a0; o[64 + lane] = a1;
}

// ---------------- launcher ----------------
extern "C" void kernel_launch(void* const* d_in, const int* in_sizes, int n_in,
                              void* d_out, int out_size, void* d_ws, size_t ws_size,
                              hipStream_t stream) {
  const float* x    = (const float*)d_in[0];
  const float* pos  = (const float*)d_in[1];
  const int*   ei   = (const int*)d_in[2];
  const float* Wd0  = (const float*)d_in[3];
  const float* bd0  = (const float*)d_in[4];
  const float* Wd1  = (const float*)d_in[5];
  const float* bd1  = (const float*)d_in[6];
  const float* Wu0  = (const float*)d_in[7];
  const float* bu0  = (const float*)d_in[8];
  const float* Wu1  = (const float*)d_in[9];
  const float* bu1  = (const float*)d_in[10];
  const float* Wl   = (const float*)d_in[11];
  const float* bl   = (const float*)d_in[12];
  float* out = (float*)d_out;

  char* ws = (char*)d_ws;
  size_t off = 0;
  auto alloc = [&](size_t bytes) -> char* {
    char* p = ws + off;
    off = (off + bytes + 255) & ~(size_t)255;
    return p;
  };
  float* bufA   = (float*)alloc((size_t)N0 * HF * 4);
  float* bufB   = (float*)alloc((size_t)N0 * HF * 4);
  float* bufC   = (float*)alloc((size_t)N1 * HF * 4);
  float* x2     = (float*)alloc((size_t)N2 * HF * 4);
  int*   offs0  = (int*)alloc((N0 + 1) * 4);
  int*   srcl0  = (int*)alloc(E0C * 4);
  int*   cnt    = (int*)alloc(N0 * 4);
  int*   cursor = (int*)alloc(N0 * 4);
  float* dinv0  = (float*)alloc(N0 * 4);
  int*   perm0  = (int*)alloc(N1 * 4);
  float* pos1   = (float*)alloc(N1 * 2 * 4);
  int*   src1   = (int*)alloc(N1 * 6 * 4);
  int*   perm1  = (int*)alloc(N2 * 4);
  float* pos2   = (float*)alloc(N2 * 2 * 4);
  int*   iidx   = (int*)alloc((size_t)N0 * 6 * 4);
  float* iw     = (float*)alloc((size_t)N0 * 6 * 4);
  float* iwsum  = (float*)alloc(N0 * 4);

  float* h1   = bufB;                 // [N1,H]
  float* x1f  = bufB + (size_t)N1 * HF;
  float* hu0  = bufB;
  float* xu0f = bufB + (size_t)N1 * HF;

  // level-0 CSR
  hipMemsetAsync(cnt, 0, N0 * 4, stream);
  hipMemsetAsync(cursor, 0, N0 * 4, stream);
  count_deg<<<E0C / 256, 256, 0, stream>>>(ei + E0C, cnt, E0C);
  scan_offsets<<<1, 1024, 0, stream>>>(cnt, offs0, dinv0);
  fill_csr<<<E0C / 256, 256, 0, stream>>>(ei, ei + E0C, offs0, cursor, srcl0, E0C);

  // down 0
  gemm_f32<128, 64, 16><<<dim3(N0 / 128, HF / 64), 256, 0, stream>>>(
      x, Wd0, nullptr, bufA, N0, HF, FIN, 0);
  gcn_agg_csr<<<N0 / 4, 256, 0, stream>>>(bufA, offs0, srcl0, dinv0, bd0, bufB, N0);
  fps_kernel<N0, 16, N1><<<1, 1024, 0, stream>>>(pos, perm0, pos1);
  gather_rows<<<N1 / 4, 256, 0, stream>>>(bufB, perm0, bufC, N1);  // x1 -> bufC
  knn_graph_kernel<N1, 6><<<N1 / 256, 256, 0, stream>>>(pos1, src1);

  // down 1
  gemm_f32<128, 64, 16><<<dim3(N1 / 128, HF / 64), 256, 0, stream>>>(
      bufC, Wd1, nullptr, h1, N1, HF, HF, 0);
  gcn_agg_knn<6><<<N1 / 4, 256, 0, stream>>>(h1, src1, bd1, x1f, N1);
  fps_kernel<N1, 4, N2><<<1, 1024, 0, stream>>>(pos1, perm1, pos2);
  gather_rows<<<N2 / 4, 256, 0, stream>>>(x1f, perm1, x2, N2);

  // up 0: interpolate level2 -> level1, GCN on knn1 edges
  interp_topk<N2, 6><<<N1 / 256, 256, 0, stream>>>(pos1, pos2, iidx, iw, iwsum);
  interp_combine<6><<<N1 / 4, 256, 0, stream>>>(x2, iidx, iw, iwsum, bufC, N1); // xi1 -> bufC
  gemm_f32<128, 64, 16><<<dim3(N1 / 128, HF / 64), 256, 0, stream>>>(
      bufC, Wu0, nullptr, hu0, N1, HF, HF, 0);
  gcn_agg_knn<6><<<N1 / 4, 256, 0, stream>>>(hu0, src1, bu0, xu0f, N1);

  // up 1: interpolate level1 -> level0, GCN on level-0 edges
  interp_topk<N1, 6><<<N0 / 256, 256, 0, stream>>>(pos, pos1, iidx, iw, iwsum);
  interp_combine<6><<<N0 / 4, 256, 0, stream>>>(xu0f, iidx, iw, iwsum, bufA, N0); // xi0 -> bufA
  gemm_f32<128, 64, 16><<<dim3(N0 / 128, HF / 64), 256, 0, stream>>>(
      bufA, Wu1, nullptr, bufB, N0, HF, HF, 0);  // hu1 -> bufB (full)
  gcn_agg_csr<<<N0 / 4, 256, 0, stream>>>(bufB, offs0, srcl0, dinv0, bu1, bufA, N0); // xu1f -> bufA

  // final linear
  gemm_f32<128, 64, 16><<<dim3(N0 / 128, HF / 64), 256, 0, stream>>>(
      bufA, Wl, bl, out, N0, HF, HF, 1);
}

// Round 2
// 9219.344 us; speedup vs baseline: 1.3870x; 1.3870x over previous
//
#include <hip/hip_runtime.h>

#define N0 16384
#define N1 4096
#define N2 1024
#define E0C 131072
#define FIN 384
#define HF 512

// ---------------- helpers ----------------
__device__ inline float4 f4fma(float w, const float4 v, float4 a) {
  a.x = fmaf(w, v.x, a.x); a.y = fmaf(w, v.y, a.y);
  a.z = fmaf(w, v.z, a.z); a.w = fmaf(w, v.w, a.w);
  return a;
}

// ---------------- CSR build for level-0 random graph ----------------
__global__ __launch_bounds__(256)
void count_deg(const int* __restrict__ dst, int* __restrict__ cnt, int E) {
  int e = blockIdx.x * 256 + threadIdx.x;
  if (e < E) atomicAdd(&cnt[dst[e]], 1);
}

__global__ __launch_bounds__(1024)
void scan_offsets(const int* __restrict__ cnt, int* __restrict__ offs,
                  float* __restrict__ dinv) {
  __shared__ int ts[1024];
  const int t = threadIdx.x;
  int local[16];
  int sum = 0;
  #pragma unroll
  for (int j = 0; j < 16; ++j) { local[j] = cnt[t * 16 + j]; sum += local[j]; }
  ts[t] = sum;
  __syncthreads();
  for (int off = 1; off < 1024; off <<= 1) {
    int v = (t >= off) ? ts[t - off] : 0;
    __syncthreads();
    ts[t] += v;
    __syncthreads();
  }
  int run = ts[t] - sum;
  #pragma unroll
  for (int j = 0; j < 16; ++j) {
    offs[t * 16 + j] = run;
    dinv[t * 16 + j] = 1.0f / sqrtf((float)local[j] + 2.0f);
    run += local[j];
  }
  if (t == 1023) offs[N0] = run;
}

__global__ __launch_bounds__(256)
void fill_csr(const int* __restrict__ src, const int* __restrict__ dst,
              const int* __restrict__ offs, int* __restrict__ cursor,
              int* __restrict__ srcl, int E) {
  int e = blockIdx.x * 256 + threadIdx.x;
  if (e < E) {
    int d = dst[e];
    int p = atomicAdd(&cursor[d], 1);
    srcl[offs[d] + p] = src[e];
  }
}

// ---------------- fp32 GEMM ----------------
template<int BM, int BN, int BK>
__global__ __launch_bounds__(256)
void gemm_f32(const float* __restrict__ A, const float* __restrict__ W,
              const float* __restrict__ bias, float* __restrict__ C,
              int M, int N, int K, int addBias) {
  __shared__ float As[BK][BM + 4];
  __shared__ float Ws[BK][BN];
  const int tid = threadIdx.x;
  const int bm = blockIdx.x * BM;
  const int bn = blockIdx.y * BN;
  const int tx = tid & 15;
  const int ty = tid >> 4;
  float acc[8][4];
  #pragma unroll
  for (int i = 0; i < 8; ++i)
    #pragma unroll
    for (int j = 0; j < 4; ++j) acc[i][j] = 0.f;

  for (int k0 = 0; k0 < K; k0 += BK) {
    #pragma unroll
    for (int h = 0; h < (BM * BK) / (256 * 4); ++h) {
      int q = tid + h * 256;
      int r = q >> 2;
      int c = (q & 3) << 2;
      float4 v = *(const float4*)(A + (size_t)(bm + r) * K + k0 + c);
      As[c][r] = v.x; As[c + 1][r] = v.y; As[c + 2][r] = v.z; As[c + 3][r] = v.w;
    }
    {
      int kk = tid >> 4;
      int n = (tid & 15) << 2;
      *(float4*)(&Ws[kk][n]) = *(const float4*)(W + (size_t)(k0 + kk) * N + bn + n);
    }
    __syncthreads();
    #pragma unroll
    for (int kk = 0; kk < BK; ++kk) {
      float4 b4 = *(const float4*)(&Ws[kk][tx << 2]);
      float4 a0 = *(const float4*)(&As[kk][ty << 3]);
      float4 a1 = *(const float4*)(&As[kk][(ty << 3) + 4]);
      float a[8] = {a0.x, a0.y, a0.z, a0.w, a1.x, a1.y, a1.z, a1.w};
      float b[4] = {b4.x, b4.y, b4.z, b4.w};
      #pragma unroll
      for (int i = 0; i < 8; ++i)
        #pragma unroll
        for (int j = 0; j < 4; ++j)
          acc[i][j] = fmaf(a[i], b[j], acc[i][j]);
    }
    __syncthreads();
  }
  #pragma unroll
  for (int i = 0; i < 8; ++i) {
    int row = bm + (ty << 3) + i;
    float4 o = {acc[i][0], acc[i][1], acc[i][2], acc[i][3]};
    if (addBias) {
      const float4 bb = *(const float4*)(bias + bn + (tx << 2));
      o.x += bb.x; o.y += bb.y; o.z += bb.z; o.w += bb.w;
    }
    *(float4*)(C + (size_t)row * N + bn + (tx << 2)) = o;
  }
}

// ---------------- GCN aggregation (CSR) ----------------
__global__ __launch_bounds__(256)
void gcn_agg_csr(const float* __restrict__ h, const int* __restrict__ offs,
                 const int* __restrict__ srcl, const float* __restrict__ dinv,
                 const float* __restrict__ bias, float* __restrict__ out, int n) {
  const int wid = threadIdx.x >> 6, lane = threadIdx.x & 63;
  const int node = blockIdx.x * 4 + wid;
  if (node >= n) return;
  const float di = dinv[node];
  const int s0 = offs[node], s1 = offs[node + 1];
  float4 a0 = {0, 0, 0, 0}, a1 = {0, 0, 0, 0};
  for (int e = s0; e < s1; ++e) {
    const int s = srcl[e];
    const float w = dinv[s] * di;
    const float4* r = (const float4*)(h + (size_t)s * HF);
    a0 = f4fma(w, r[lane], a0);
    a1 = f4fma(w, r[64 + lane], a1);
  }
  const float sw = 2.0f * di * di;
  const float4* rs = (const float4*)(h + (size_t)node * HF);
  a0 = f4fma(sw, rs[lane], a0);
  a1 = f4fma(sw, rs[64 + lane], a1);
  const float4 b0 = *(const float4*)(bias + (lane << 2));
  const float4 b1 = *(const float4*)(bias + 256 + (lane << 2));
  a0.x = fmaxf(a0.x + b0.x, 0.f); a0.y = fmaxf(a0.y + b0.y, 0.f);
  a0.z = fmaxf(a0.z + b0.z, 0.f); a0.w = fmaxf(a0.w + b0.w, 0.f);
  a1.x = fmaxf(a1.x + b1.x, 0.f); a1.y = fmaxf(a1.y + b1.y, 0.f);
  a1.z = fmaxf(a1.z + b1.z, 0.f); a1.w = fmaxf(a1.w + b1.w, 0.f);
  float4* o = (float4*)(out + (size_t)node * HF);
  o[lane] = a0; o[64 + lane] = a1;
}

// ---------------- GCN aggregation (kNN) ----------------
template<int K>
__global__ __launch_bounds__(256)
void gcn_agg_knn(const float* __restrict__ h, const int* __restrict__ nbr,
                 const float* __restrict__ bias, float* __restrict__ out, int n) {
  const int wid = threadIdx.x >> 6, lane = threadIdx.x & 63;
  const int node = blockIdx.x * 4 + wid;
  if (node >= n) return;
  const float di = 1.0f / sqrtf((float)(K + 2));
  const float w = di * di;
  float4 a0 = {0, 0, 0, 0}, a1 = {0, 0, 0, 0};
  #pragma unroll
  for (int j = 0; j < K; ++j) {
    const int s = nbr[node * K + j];
    const float4* r = (const float4*)(h + (size_t)s * HF);
    a0 = f4fma(w, r[lane], a0);
    a1 = f4fma(w, r[64 + lane], a1);
  }
  const float sw = 2.0f * di * di;
  const float4* rs = (const float4*)(h + (size_t)node * HF);
  a0 = f4fma(sw, rs[lane], a0);
  a1 = f4fma(sw, rs[64 + lane], a1);
  const float4 b0 = *(const float4*)(bias + (lane << 2));
  const float4 b1 = *(const float4*)(bias + 256 + (lane << 2));
  a0.x = fmaxf(a0.x + b0.x, 0.f); a0.y = fmaxf(a0.y + b0.y, 0.f);
  a0.z = fmaxf(a0.z + b0.z, 0.f); a0.w = fmaxf(a0.w + b0.w, 0.f);
  a1.x = fmaxf(a1.x + b1.x, 0.f); a1.y = fmaxf(a1.y + b1.y, 0.f);
  a1.z = fmaxf(a1.z + b1.z, 0.f); a1.w = fmaxf(a1.w + b1.w, 0.f);
  float4* o = (float4*)(out + (size_t)node * HF);
  o[lane] = a0; o[64 + lane] = a1;
}

// ---------------- spatial binning (counting sort into 32x32 cells) ----------------
__global__ __launch_bounds__(256)
void bin_hist(const float* __restrict__ pos, int* __restrict__ cid,
              int* __restrict__ hist, int n) {
  int i = blockIdx.x * 256 + threadIdx.x;
  if (i >= n) return;
  float x = pos[2 * i], y = pos[2 * i + 1];
  int cxi = (int)(x * 0.32f); cxi = cxi < 0 ? 0 : (cxi > 31 ? 31 : cxi);
  int cyi = (int)(y * 0.32f); cyi = cyi < 0 ? 0 : (cyi > 31 ? 31 : cyi);
  int c = cyi * 32 + cxi;
  cid[i] = c;
  atomicAdd(&hist[c], 1);
}

__global__ __launch_bounds__(1024)
void bin_scan(const int* __restrict__ hist, int* __restrict__ offs) {
  __shared__ int ts[1024];
  const int t = threadIdx.x;
  int v = hist[t];
  ts[t] = v;
  __syncthreads();
  for (int off = 1; off < 1024; off <<= 1) {
    int u = (t >= off) ? ts[t - off] : 0;
    __syncthreads();
    ts[t] += u;
    __syncthreads();
  }
  offs[t] = ts[t] - v;
  if (t == 1023) offs[1024] = ts[t];
}

__global__ __launch_bounds__(256)
void bin_scatter(const float* __restrict__ pos, const int* __restrict__ cid,
                 const int* __restrict__ offs, int* __restrict__ cursor,
                 float* __restrict__ sx, float* __restrict__ sy,
                 int* __restrict__ sid, int n) {
  int i = blockIdx.x * 256 + threadIdx.x;
  if (i >= n) return;
  int c = cid[i];
  int p = atomicAdd(&cursor[c], 1);
  int slot = offs[c] + p;
  sx[slot] = pos[2 * i];
  sy[slot] = pos[2 * i + 1];
  sid[slot] = i;
}

// ---------------- pruned FPS ----------------
template<int NN>
__device__ __forceinline__ unsigned ror16(unsigned v) {
  return (unsigned)__builtin_amdgcn_update_dpp(0, (int)v, 0x120 | NN, 0xF, 0xF, false);
}

__device__ __forceinline__ void comb(unsigned& hi, unsigned& lo, float& x, float& y,
                                     unsigned ohi, unsigned olo, float ox, float oy) {
  unsigned long long a = ((unsigned long long)hi << 32) | lo;
  unsigned long long b = ((unsigned long long)ohi << 32) | olo;
  if (b > a) { hi = ohi; lo = olo; x = ox; y = oy; }
}

// key = (bits(dist) << 32) | ~orig_idx  -> u64 max == (max dist, tie: min idx)
template<int N, int CHUNK, int NKEEP>
__global__ __launch_bounds__(1024)
void fps_pruned(const float* __restrict__ pos0,
                const float* __restrict__ sx, const float* __restrict__ sy,
                const int* __restrict__ sid,
                int* __restrict__ perm, float* __restrict__ pos_out) {
  const int t = threadIdx.x;
  const int base = t * CHUNK;
  float px[CHUNK], py[CHUNK], d[CHUNK];
  int id[CHUNK];
  float xmn = 3.4e38f, xmx = -3.4e38f, ymn = 3.4e38f, ymx = -3.4e38f;
  #pragma unroll
  for (int j = 0; j < CHUNK; ++j) {
    px[j] = sx[base + j]; py[j] = sy[base + j]; id[j] = sid[base + j];
    xmn = fminf(xmn, px[j]); xmx = fmaxf(xmx, px[j]);
    ymn = fminf(ymn, py[j]); ymx = fmaxf(ymx, py[j]);
  }
  float cx = pos0[0], cy = pos0[1];
  if (t == 0) { perm[0] = 0; pos_out[0] = cx; pos_out[1] = cy; }

  // init dist with c0, track chunk candidate
  unsigned chi = 0, clo = 0; float ccx = 0.f, ccy = 0.f;
  {
    unsigned long long best = 0;
    #pragma unroll
    for (int j = 0; j < CHUNK; ++j) {
      float dx = __fsub_rn(px[j], cx), dy = __fsub_rn(py[j], cy);
      float nd = __fadd_rn(__fmul_rn(dx, dx), __fmul_rn(dy, dy));
      d[j] = nd;
      unsigned long long kv = ((unsigned long long)__float_as_uint(nd) << 32) |
                              (unsigned)(~(unsigned)id[j]);
      if (kv > best) { best = kv; ccx = px[j]; ccy = py[j]; }
    }
    chi = (unsigned)(best >> 32); clo = (unsigned)best;
  }
  float cmaxv = __uint_as_float(chi);

  __shared__ float4 e1[64];
  __shared__ float bc[2];

  for (int i = 1; i < NKEEP; ++i) {
    // ---- reduce (chunk candidates -> global winner) ----
    unsigned hi = chi, lo = clo; float wx = ccx, wy = ccy;
    {
      unsigned ohi, olo, ox, oy;
      ohi = ror16<1>(hi); olo = ror16<1>(lo); ox = ror16<1>(__float_as_uint(wx)); oy = ror16<1>(__float_as_uint(wy));
      comb(hi, lo, wx, wy, ohi, olo, __uint_as_float(ox), __uint_as_float(oy));
      ohi = ror16<2>(hi); olo = ror16<2>(lo); ox = ror16<2>(__float_as_uint(wx)); oy = ror16<2>(__float_as_uint(wy));
      comb(hi, lo, wx, wy, ohi, olo, __uint_as_float(ox), __uint_as_float(oy));
      ohi = ror16<4>(hi); olo = ror16<4>(lo); ox = ror16<4>(__float_as_uint(wx)); oy = ror16<4>(__float_as_uint(wy));
      comb(hi, lo, wx, wy, ohi, olo, __uint_as_float(ox), __uint_as_float(oy));
      ohi = ror16<8>(hi); olo = ror16<8>(lo); ox = ror16<8>(__float_as_uint(wx)); oy = ror16<8>(__float_as_uint(wy));
      comb(hi, lo, wx, wy, ohi, olo, __uint_as_float(ox), __uint_as_float(oy));
    }
    if ((t & 15) == 0)
      e1[t >> 4] = make_float4(__uint_as_float(hi), __uint_as_float(lo), wx, wy);
    __syncthreads();
    if (t < 16) {
      float4 a = e1[t];
      unsigned fhi = __float_as_uint(a.x), flo = __float_as_uint(a.y);
      float fx = a.z, fy = a.w;
      float4 b = e1[t + 16];
      comb(fhi, flo, fx, fy, __float_as_uint(b.x), __float_as_uint(b.y), b.z, b.w);
      b = e1[t + 32];
      comb(fhi, flo, fx, fy, __float_as_uint(b.x), __float_as_uint(b.y), b.z, b.w);
      b = e1[t + 48];
      comb(fhi, flo, fx, fy, __float_as_uint(b.x), __float_as_uint(b.y), b.z, b.w);
      unsigned ohi, olo, ox, oy;
      ohi = ror16<1>(fhi); olo = ror16<1>(flo); ox = ror16<1>(__float_as_uint(fx)); oy = ror16<1>(__float_as_uint(fy));
      comb(fhi, flo, fx, fy, ohi, olo, __uint_as_float(ox), __uint_as_float(oy));
      ohi = ror16<2>(fhi); olo = ror16<2>(flo); ox = ror16<2>(__float_as_uint(fx)); oy = ror16<2>(__float_as_uint(fy));
      comb(fhi, flo, fx, fy, ohi, olo, __uint_as_float(ox), __uint_as_float(oy));
      ohi = ror16<4>(fhi); olo = ror16<4>(flo); ox = ror16<4>(__float_as_uint(fx)); oy = ror16<4>(__float_as_uint(fy));
      comb(fhi, flo, fx, fy, ohi, olo, __uint_as_float(ox), __uint_as_float(oy));
      ohi = ror16<8>(fhi); olo = ror16<8>(flo); ox = ror16<8>(__float_as_uint(fx)); oy = ror16<8>(__float_as_uint(fy));
      comb(fhi, flo, fx, fy, ohi, olo, __uint_as_float(ox), __uint_as_float(oy));
      if (t == 0) {
        int idx = (int)(~flo);
        perm[i] = idx;
        pos_out[2 * i] = fx; pos_out[2 * i + 1] = fy;
        bc[0] = fx; bc[1] = fy;
      }
    }
    __syncthreads();
    cx = bc[0]; cy = bc[1];

    // ---- pruned update ----
    float mdx = fmaxf(fmaxf(__fsub_rn(xmn, cx), __fsub_rn(cx, xmx)), 0.f);
    float mdy = fmaxf(fmaxf(__fsub_rn(ymn, cy), __fsub_rn(cy, ymx)), 0.f);
    float mb = mdx * mdx + mdy * mdy;
    if (!(mb * 0.99999f > cmaxv)) {
      unsigned long long best = 0;
      float nccx = 0.f, nccy = 0.f;
      #pragma unroll
      for (int j = 0; j < CHUNK; ++j) {
        float dx = __fsub_rn(px[j], cx), dy = __fsub_rn(py[j], cy);
        float nd = __fadd_rn(__fmul_rn(dx, dx), __fmul_rn(dy, dy));
        float dn = fminf(d[j], nd);
        d[j] = dn;
        unsigned long long kv = ((unsigned long long)__float_as_uint(dn) << 32) |
                                (unsigned)(~(unsigned)id[j]);
        if (kv > best) { best = kv; nccx = px[j]; nccy = py[j]; }
      }
      chi = (unsigned)(best >> 32); clo = (unsigned)best;
      ccx = nccx; ccy = nccy;
      cmaxv = __uint_as_float(chi);
    }
  }
}

// ---------------- row gather ----------------
__global__ __launch_bounds__(256)
void gather_rows(const float* __restrict__ xin, const int* __restrict__ perm,
                 float* __restrict__ xout, int n) {
  const int wid = threadIdx.x >> 6, lane = threadIdx.x & 63;
  const int i = blockIdx.x * 4 + wid;
  if (i >= n) return;
  const int s = perm[i];
  const float4* r = (const float4*)(xin + (size_t)s * HF);
  float4* o = (float4*)(xout + (size_t)i * HF);
  o[lane] = r[lane];
  o[64 + lane] = r[64 + lane];
}

// ---------------- kNN graph ----------------
template<int NPTS, int K>
__global__ __launch_bounds__(256)
void knn_graph_kernel(const float* __restrict__ pos, int* __restrict__ srcout) {
  __shared__ float sx[NPTS], sy[NPTS], ss[NPTS];
  const int tid = threadIdx.x;
  for (int idx = tid; idx < NPTS; idx += 256) {
    float x = pos[2 * idx], y = pos[2 * idx + 1];
    sx[idx] = x; sy[idx] = y;
    ss[idx] = __fadd_rn(__fmul_rn(x, x), __fmul_rn(y, y));
  }
  __syncthreads();
  const int q = blockIdx.x * 256 + tid;
  const float qx = sx[q], qy = sy[q], qs = ss[q];
  float bd[K]; int bi[K];
  #pragma unroll
  for (int m = 0; m < K; ++m) { bd[m] = 3.4e38f; bi[m] = 0; }
  for (int j = 0; j < NPTS; ++j) {
    if (j == q) continue;
    float dot = __fadd_rn(__fmul_rn(qx, sx[j]), __fmul_rn(qy, sy[j]));
    float d2 = fmaxf(__fsub_rn(__fadd_rn(qs, ss[j]), __fmul_rn(2.0f, dot)), 0.0f);
    if (d2 < bd[K - 1]) {
      bool pr[K];
      #pragma unroll
      for (int m = 0; m < K; ++m) pr[m] = (d2 < bd[m]);
      #pragma unroll
      for (int m = K - 1; m >= 1; --m) {
        bd[m] = pr[m] ? (pr[m - 1] ? bd[m - 1] : d2) : bd[m];
        bi[m] = pr[m] ? (pr[m - 1] ? bi[m - 1] : j) : bi[m];
      }
      if (pr[0]) { bd[0] = d2; bi[0] = j; }
    }
  }
  #pragma unroll
  for (int m = 0; m < K; ++m) srcout[q * K + m] = bi[m];
}

// ---------------- kNN interpolate ----------------
template<int NX, int K>
__global__ __launch_bounds__(256)
void interp_topk(const float* __restrict__ posy, const float* __restrict__ posx,
                 int* __restrict__ oidx, float* __restrict__ ow,
                 float* __restrict__ owsum) {
  __shared__ float sx[NX], sy[NX], ss[NX];
  const int tid = threadIdx.x;
  for (int idx = tid; idx < NX; idx += 256) {
    float x = posx[2 * idx], y = posx[2 * idx + 1];
    sx[idx] = x; sy[idx] = y;
    ss[idx] = __fadd_rn(__fmul_rn(x, x), __fmul_rn(y, y));
  }
  __syncthreads();
  const int q = blockIdx.x * 256 + tid;
  const float qx = posy[2 * q], qy = posy[2 * q + 1];
  const float qs = __fadd_rn(__fmul_rn(qx, qx), __fmul_rn(qy, qy));
  float bd[K]; int bi[K];
  #pragma unroll
  for (int m = 0; m < K; ++m) { bd[m] = 3.4e38f; bi[m] = 0; }
  for (int j = 0; j < NX; ++j) {
    float dot = __fadd_rn(__fmul_rn(qx, sx[j]), __fmul_rn(qy, sy[j]));
    float d2 = fmaxf(__fsub_rn(__fadd_rn(qs, ss[j]), __fmul_rn(2.0f, dot)), 0.0f);
    if (d2 < bd[K - 1]) {
      bool pr[K];
      #pragma unroll
      for (int m = 0; m < K; ++m) pr[m] = (d2 < bd[m]);
      #pragma unroll
      for (int m = K - 1; m >= 1; --m) {
        bd[m] = pr[m] ? (pr[m - 1] ? bd[m - 1] : d2) : bd[m];
        bi[m] = pr[m] ? (pr[m - 1] ? bi[m - 1] : j) : bi[m];
      }
      if (pr[0]) { bd[0] = d2; bi[0] = j; }
    }
  }
  float wsum = 0.f;
  #pragma unroll
  for (int m = 0; m < K; ++m) {
    float w = 1.0f / fmaxf(bd[m], 1e-16f);
    ow[q * K + m] = w;
    oidx[q * K + m] = bi[m];
    wsum = __fadd_rn(wsum, w);
  }
  owsum[q] = wsum;
}

template<int K>
__global__ __launch_bounds__(256)
void interp_combine(const float* __restrict__ xin, const int* __restrict__ idx,
                    const float* __restrict__ w, const float* __restrict__ wsum,
                    float* __restrict__ out, int ny) {
  const int wid = threadIdx.x >> 6, lane = threadIdx.x & 63;
  const int q = blockIdx.x * 4 + wid;
  if (q >= ny) return;
  float4 a0 = {0, 0, 0, 0}, a1 = {0, 0, 0, 0};
  #pragma unroll
  for (int m = 0; m < K; ++m) {
    const int s = idx[q * K + m];
    const float wk = w[q * K + m];
    const float4* r = (const float4*)(xin + (size_t)s * HF);
    a0 = f4fma(wk, r[lane], a0);
    a1 = f4fma(wk, r[64 + lane], a1);
  }
  const float inv = wsum[q];
  a0.x /= inv; a0.y /= inv; a0.z /= inv; a0.w /= inv;
  a1.x /= inv; a1.y /= inv; a1.z /= inv; a1.w /= inv;
  float4* o = (float4*)(out + (size_t)q * HF);
  o[lane] = a0; o[64 + lane] = a1;
}

// ---------------- launcher ----------------
extern "C" void kernel_launch(void* const* d_in, const int* in_sizes, int n_in,
                              void* d_out, int out_size, void* d_ws, size_t ws_size,
                              hipStream_t stream) {
  const float* x    = (const float*)d_in[0];
  const float* pos  = (const float*)d_in[1];
  const int*   ei   = (const int*)d_in[2];
  const float* Wd0  = (const float*)d_in[3];
  const float* bd0  = (const float*)d_in[4];
  const float* Wd1  = (const float*)d_in[5];
  const float* bd1  = (const float*)d_in[6];
  const float* Wu0  = (const float*)d_in[7];
  const float* bu0  = (const float*)d_in[8];
  const float* Wu1  = (const float*)d_in[9];
  const float* bu1  = (const float*)d_in[10];
  const float* Wl   = (const float*)d_in[11];
  const float* bl   = (const float*)d_in[12];
  float* out = (float*)d_out;

  char* ws = (char*)d_ws;
  size_t off = 0;
  auto alloc = [&](size_t bytes) -> char* {
    char* p = ws + off;
    off = (off + bytes + 255) & ~(size_t)255;
    return p;
  };
  float* bufA   = (float*)alloc((size_t)N0 * HF * 4);
  float* bufB   = (float*)alloc((size_t)N0 * HF * 4);
  float* bufC   = (float*)alloc((size_t)N1 * HF * 4);
  float* x2     = (float*)alloc((size_t)N2 * HF * 4);
  int*   offs0  = (int*)alloc((N0 + 1) * 4);
  int*   srcl0  = (int*)alloc(E0C * 4);
  int*   cnt    = (int*)alloc(N0 * 4);
  int*   cursor = (int*)alloc(N0 * 4);
  float* dinv0  = (float*)alloc(N0 * 4);
  int*   perm0  = (int*)alloc(N1 * 4);
  float* pos1   = (float*)alloc(N1 * 2 * 4);
  int*   src1   = (int*)alloc(N1 * 6 * 4);
  int*   perm1  = (int*)alloc(N2 * 4);
  float* pos2   = (float*)alloc(N2 * 2 * 4);
  int*   iidx   = (int*)alloc((size_t)N0 * 6 * 4);
  float* iw     = (float*)alloc((size_t)N0 * 6 * 4);
  float* iwsum  = (float*)alloc(N0 * 4);
  // binning scratch
  float* bsx    = (float*)alloc(N0 * 4);
  float* bsy    = (float*)alloc(N0 * 4);
  int*   bsid   = (int*)alloc(N0 * 4);
  int*   bcid   = (int*)alloc(N0 * 4);
  int*   bhist  = (int*)alloc(1024 * 4);
  int*   bcur   = (int*)alloc(1024 * 4);
  int*   boffs  = (int*)alloc(1025 * 4);

  float* h1   = bufB;
  float* x1f  = bufB + (size_t)N1 * HF;
  float* hu0  = bufB;
  float* xu0f = bufB + (size_t)N1 * HF;

  // level-0 CSR
  hipMemsetAsync(cnt, 0, N0 * 4, stream);
  hipMemsetAsync(cursor, 0, N0 * 4, stream);
  count_deg<<<E0C / 256, 256, 0, stream>>>(ei + E0C, cnt, E0C);
  scan_offsets<<<1, 1024, 0, stream>>>(cnt, offs0, dinv0);
  fill_csr<<<E0C / 256, 256, 0, stream>>>(ei, ei + E0C, offs0, cursor, srcl0, E0C);

  // bin pos (level 0) for FPS0
  hipMemsetAsync(bhist, 0, 1024 * 4, stream);
  hipMemsetAsync(bcur, 0, 1024 * 4, stream);
  bin_hist<<<N0 / 256, 256, 0, stream>>>(pos, bcid, bhist, N0);
  bin_scan<<<1, 1024, 0, stream>>>(bhist, boffs);
  bin_scatter<<<N0 / 256, 256, 0, stream>>>(pos, bcid, boffs, bcur, bsx, bsy, bsid, N0);

  // down 0
  gemm_f32<128, 64, 16><<<dim3(N0 / 128, HF / 64), 256, 0, stream>>>(
      x, Wd0, nullptr, bufA, N0, HF, FIN, 0);
  gcn_agg_csr<<<N0 / 4, 256, 0, stream>>>(bufA, offs0, srcl0, dinv0, bd0, bufB, N0);
  fps_pruned<N0, 16, N1><<<1, 1024, 0, stream>>>(pos, bsx, bsy, bsid, perm0, pos1);
  gather_rows<<<N1 / 4, 256, 0, stream>>>(bufB, perm0, bufC, N1);
  knn_graph_kernel<N1, 6><<<N1 / 256, 256, 0, stream>>>(pos1, src1);

  // bin pos1 for FPS1
  hipMemsetAsync(bhist, 0, 1024 * 4, stream);
  hipMemsetAsync(bcur, 0, 1024 * 4, stream);
  bin_hist<<<N1 / 256, 256, 0, stream>>>(pos1, bcid, bhist, N1);
  bin_scan<<<1, 1024, 0, stream>>>(bhist, boffs);
  bin_scatter<<<N1 / 256, 256, 0, stream>>>(pos1, bcid, boffs, bcur, bsx, bsy, bsid, N1);

  // down 1
  gemm_f32<128, 64, 16><<<dim3(N1 / 128, HF / 64), 256, 0, stream>>>(
      bufC, Wd1, nullptr, h1, N1, HF, HF, 0);
  gcn_agg_knn<6><<<N1 / 4, 256, 0, stream>>>(h1, src1, bd1, x1f, N1);
  fps_pruned<N1, 4, N2><<<1, 1024, 0, stream>>>(pos1, bsx, bsy, bsid, perm1, pos2);
  gather_rows<<<N2 / 4, 256, 0, stream>>>(x1f, perm1, x2, N2);

  // up 0
  interp_topk<N2, 6><<<N1 / 256, 256, 0, stream>>>(pos1, pos2, iidx, iw, iwsum);
  interp_combine<6><<<N1 / 4, 256, 0, stream>>>(x2, iidx, iw, iwsum, bufC, N1);
  gemm_f32<128, 64, 16><<<dim3(N1 / 128, HF / 64), 256, 0, stream>>>(
      bufC, Wu0, nullptr, hu0, N1, HF, HF, 0);
  gcn_agg_knn<6><<<N1 / 4, 256, 0, stream>>>(hu0, src1, bu0, xu0f, N1);

  // up 1
  interp_topk<N1, 6><<<N0 / 256, 256, 0, stream>>>(pos, pos1, iidx, iw, iwsum);
  interp_combine<6><<<N0 / 4, 256, 0, stream>>>(xu0f, iidx, iw, iwsum, bufA, N0);
  gemm_f32<128, 64, 16><<<dim3(N0 / 128, HF / 64), 256, 0, stream>>>(
      bufA, Wu1, nullptr, bufB, N0, HF, HF, 0);
  gcn_agg_csr<<<N0 / 4, 256, 0, stream>>>(bufB, offs0, srcl0, dinv0, bu1, bufA, N0);

  // final linear
  gemm_f32<128, 64, 16><<<dim3(N0 / 128, HF / 64), 256, 0, stream>>>(
      bufA, Wl, bl, out, N0, HF, HF, 1);
}

// Round 3
// 8044.798 us; speedup vs baseline: 1.5895x; 1.1460x over previous
//
#include <hip/hip_runtime.h>

#define N0 16384
#define N1 4096
#define N2 1024
#define E0C 131072
#define FIN 384
#define HF 512

// ---------------- helpers ----------------
__device__ inline float4 f4fma(float w, const float4 v, float4 a) {
  a.x = fmaf(w, v.x, a.x); a.y = fmaf(w, v.y, a.y);
  a.z = fmaf(w, v.z, a.z); a.w = fmaf(w, v.w, a.w);
  return a;
}

// ---------------- CSR build for level-0 random graph ----------------
__global__ __launch_bounds__(256)
void count_deg(const int* __restrict__ dst, int* __restrict__ cnt, int E) {
  int e = blockIdx.x * 256 + threadIdx.x;
  if (e < E) atomicAdd(&cnt[dst[e]], 1);
}

__global__ __launch_bounds__(1024)
void scan_offsets(const int* __restrict__ cnt, int* __restrict__ offs,
                  float* __restrict__ dinv) {
  __shared__ int ts[1024];
  const int t = threadIdx.x;
  int local[16];
  int sum = 0;
  #pragma unroll
  for (int j = 0; j < 16; ++j) { local[j] = cnt[t * 16 + j]; sum += local[j]; }
  ts[t] = sum;
  __syncthreads();
  for (int off = 1; off < 1024; off <<= 1) {
    int v = (t >= off) ? ts[t - off] : 0;
    __syncthreads();
    ts[t] += v;
    __syncthreads();
  }
  int run = ts[t] - sum;
  #pragma unroll
  for (int j = 0; j < 16; ++j) {
    offs[t * 16 + j] = run;
    dinv[t * 16 + j] = 1.0f / sqrtf((float)local[j] + 2.0f);
    run += local[j];
  }
  if (t == 1023) offs[N0] = run;
}

__global__ __launch_bounds__(256)
void fill_csr(const int* __restrict__ src, const int* __restrict__ dst,
              const int* __restrict__ offs, int* __restrict__ cursor,
              int* __restrict__ srcl, int E) {
  int e = blockIdx.x * 256 + threadIdx.x;
  if (e < E) {
    int d = dst[e];
    int p = atomicAdd(&cursor[d], 1);
    srcl[offs[d] + p] = src[e];
  }
}

// ---------------- fp32 GEMM ----------------
template<int BM, int BN, int BK>
__global__ __launch_bounds__(256)
void gemm_f32(const float* __restrict__ A, const float* __restrict__ W,
              const float* __restrict__ bias, float* __restrict__ C,
              int M, int N, int K, int addBias) {
  __shared__ float As[BK][BM + 4];
  __shared__ float Ws[BK][BN];
  const int tid = threadIdx.x;
  const int bm = blockIdx.x * BM;
  const int bn = blockIdx.y * BN;
  const int tx = tid & 15;
  const int ty = tid >> 4;
  float acc[8][4];
  #pragma unroll
  for (int i = 0; i < 8; ++i)
    #pragma unroll
    for (int j = 0; j < 4; ++j) acc[i][j] = 0.f;

  for (int k0 = 0; k0 < K; k0 += BK) {
    #pragma unroll
    for (int h = 0; h < (BM * BK) / (256 * 4); ++h) {
      int q = tid + h * 256;
      int r = q >> 2;
      int c = (q & 3) << 2;
      float4 v = *(const float4*)(A + (size_t)(bm + r) * K + k0 + c);
      As[c][r] = v.x; As[c + 1][r] = v.y; As[c + 2][r] = v.z; As[c + 3][r] = v.w;
    }
    {
      int kk = tid >> 4;
      int n = (tid & 15) << 2;
      *(float4*)(&Ws[kk][n]) = *(const float4*)(W + (size_t)(k0 + kk) * N + bn + n);
    }
    __syncthreads();
    #pragma unroll
    for (int kk = 0; kk < BK; ++kk) {
      float4 b4 = *(const float4*)(&Ws[kk][tx << 2]);
      float4 a0 = *(const float4*)(&As[kk][ty << 3]);
      float4 a1 = *(const float4*)(&As[kk][(ty << 3) + 4]);
      float a[8] = {a0.x, a0.y, a0.z, a0.w, a1.x, a1.y, a1.z, a1.w};
      float b[4] = {b4.x, b4.y, b4.z, b4.w};
      #pragma unroll
      for (int i = 0; i < 8; ++i)
        #pragma unroll
        for (int j = 0; j < 4; ++j)
          acc[i][j] = fmaf(a[i], b[j], acc[i][j]);
    }
    __syncthreads();
  }
  #pragma unroll
  for (int i = 0; i < 8; ++i) {
    int row = bm + (ty << 3) + i;
    float4 o = {acc[i][0], acc[i][1], acc[i][2], acc[i][3]};
    if (addBias) {
      const float4 bb = *(const float4*)(bias + bn + (tx << 2));
      o.x += bb.x; o.y += bb.y; o.z += bb.z; o.w += bb.w;
    }
    *(float4*)(C + (size_t)row * N + bn + (tx << 2)) = o;
  }
}

// ---------------- GCN aggregation (CSR) ----------------
__global__ __launch_bounds__(256)
void gcn_agg_csr(const float* __restrict__ h, const int* __restrict__ offs,
                 const int* __restrict__ srcl, const float* __restrict__ dinv,
                 const float* __restrict__ bias, float* __restrict__ out, int n) {
  const int wid = threadIdx.x >> 6, lane = threadIdx.x & 63;
  const int node = blockIdx.x * 4 + wid;
  if (node >= n) return;
  const float di = dinv[node];
  const int s0 = offs[node], s1 = offs[node + 1];
  float4 a0 = {0, 0, 0, 0}, a1 = {0, 0, 0, 0};
  for (int e = s0; e < s1; ++e) {
    const int s = srcl[e];
    const float w = dinv[s] * di;
    const float4* r = (const float4*)(h + (size_t)s * HF);
    a0 = f4fma(w, r[lane], a0);
    a1 = f4fma(w, r[64 + lane], a1);
  }
  const float sw = 2.0f * di * di;
  const float4* rs = (const float4*)(h + (size_t)node * HF);
  a0 = f4fma(sw, rs[lane], a0);
  a1 = f4fma(sw, rs[64 + lane], a1);
  const float4 b0 = *(const float4*)(bias + (lane << 2));
  const float4 b1 = *(const float4*)(bias + 256 + (lane << 2));
  a0.x = fmaxf(a0.x + b0.x, 0.f); a0.y = fmaxf(a0.y + b0.y, 0.f);
  a0.z = fmaxf(a0.z + b0.z, 0.f); a0.w = fmaxf(a0.w + b0.w, 0.f);
  a1.x = fmaxf(a1.x + b1.x, 0.f); a1.y = fmaxf(a1.y + b1.y, 0.f);
  a1.z = fmaxf(a1.z + b1.z, 0.f); a1.w = fmaxf(a1.w + b1.w, 0.f);
  float4* o = (float4*)(out + (size_t)node * HF);
  o[lane] = a0; o[64 + lane] = a1;
}

// ---------------- GCN aggregation (kNN) ----------------
template<int K>
__global__ __launch_bounds__(256)
void gcn_agg_knn(const float* __restrict__ h, const int* __restrict__ nbr,
                 const float* __restrict__ bias, float* __restrict__ out, int n) {
  const int wid = threadIdx.x >> 6, lane = threadIdx.x & 63;
  const int node = blockIdx.x * 4 + wid;
  if (node >= n) return;
  const float di = 1.0f / sqrtf((float)(K + 2));
  const float w = di * di;
  float4 a0 = {0, 0, 0, 0}, a1 = {0, 0, 0, 0};
  #pragma unroll
  for (int j = 0; j < K; ++j) {
    const int s = nbr[node * K + j];
    const float4* r = (const float4*)(h + (size_t)s * HF);
    a0 = f4fma(w, r[lane], a0);
    a1 = f4fma(w, r[64 + lane], a1);
  }
  const float sw = 2.0f * di * di;
  const float4* rs = (const float4*)(h + (size_t)node * HF);
  a0 = f4fma(sw, rs[lane], a0);
  a1 = f4fma(sw, rs[64 + lane], a1);
  const float4 b0 = *(const float4*)(bias + (lane << 2));
  const float4 b1 = *(const float4*)(bias + 256 + (lane << 2));
  a0.x = fmaxf(a0.x + b0.x, 0.f); a0.y = fmaxf(a0.y + b0.y, 0.f);
  a0.z = fmaxf(a0.z + b0.z, 0.f); a0.w = fmaxf(a0.w + b0.w, 0.f);
  a1.x = fmaxf(a1.x + b1.x, 0.f); a1.y = fmaxf(a1.y + b1.y, 0.f);
  a1.z = fmaxf(a1.z + b1.z, 0.f); a1.w = fmaxf(a1.w + b1.w, 0.f);
  float4* o = (float4*)(out + (size_t)node * HF);
  o[lane] = a0; o[64 + lane] = a1;
}

// ---------------- spatial binning (counting sort into 32x32 cells) ----------------
__global__ __launch_bounds__(256)
void bin_hist(const float* __restrict__ pos, int* __restrict__ cid,
              int* __restrict__ hist, int n) {
  int i = blockIdx.x * 256 + threadIdx.x;
  if (i >= n) return;
  float x = pos[2 * i], y = pos[2 * i + 1];
  int cxi = (int)(x * 0.32f); cxi = cxi < 0 ? 0 : (cxi > 31 ? 31 : cxi);
  int cyi = (int)(y * 0.32f); cyi = cyi < 0 ? 0 : (cyi > 31 ? 31 : cyi);
  int c = cyi * 32 + cxi;
  cid[i] = c;
  atomicAdd(&hist[c], 1);
}

__global__ __launch_bounds__(1024)
void bin_scan(const int* __restrict__ hist, int* __restrict__ offs) {
  __shared__ int ts[1024];
  const int t = threadIdx.x;
  int v = hist[t];
  ts[t] = v;
  __syncthreads();
  for (int off = 1; off < 1024; off <<= 1) {
    int u = (t >= off) ? ts[t - off] : 0;
    __syncthreads();
    ts[t] += u;
    __syncthreads();
  }
  offs[t] = ts[t] - v;
  if (t == 1023) offs[1024] = ts[t];
}

__global__ __launch_bounds__(256)
void bin_scatter(const float* __restrict__ pos, const int* __restrict__ cid,
                 const int* __restrict__ offs, int* __restrict__ cursor,
                 float* __restrict__ sx, float* __restrict__ sy,
                 int* __restrict__ sid, int n) {
  int i = blockIdx.x * 256 + threadIdx.x;
  if (i >= n) return;
  int c = cid[i];
  int p = atomicAdd(&cursor[c], 1);
  int slot = offs[c] + p;
  sx[slot] = pos[2 * i];
  sy[slot] = pos[2 * i + 1];
  sid[slot] = i;
}

// ---------------- fast pruned FPS ----------------
template<int NN>
__device__ __forceinline__ unsigned ror16(unsigned v) {
  return (unsigned)__builtin_amdgcn_update_dpp(0, (int)v, 0x120 | NN, 0xF, 0xF, false);
}

// Chunk points live in LDS (transposed: bank = t%32, conflict-free).
// Per-chunk candidate keys ck[NCH] (u64 = dist_bits<<32 | ~orig_id) persist in
// LDS; only rescanning chunks rewrite them. One wave reduces all NCH keys.
template<int N, int NCH, int NKEEP>
__global__ __launch_bounds__(NCH)
void fps_fast(const float* __restrict__ pos0,
              const float* __restrict__ sx, const float* __restrict__ sy,
              const int* __restrict__ sid,
              int* __restrict__ perm, float* __restrict__ pos_out) {
  constexpr int CHUNK = N / NCH;
  const int t = threadIdx.x;
  const int base = t * CHUNK;

  __shared__ float pxl[N];
  __shared__ float pyl[N];
  __shared__ unsigned long long ck[NCH];
  __shared__ float2 cp[NCH];
  __shared__ float bc[2];

  float d[CHUNK];
  unsigned kid[CHUNK];
  float xmn = 3.4e38f, xmx = -3.4e38f, ymn = 3.4e38f, ymx = -3.4e38f;

  float cx = pos0[0], cy = pos0[1];
  if (t == 0) { perm[0] = 0; pos_out[0] = cx; pos_out[1] = cy; }

  // init: load chunk, stash in LDS transposed, dist to c0, chunk candidate
  {
    unsigned long long best = 0; float bx = 0.f, by = 0.f;
    #pragma unroll
    for (int j = 0; j < CHUNK; ++j) {
      float qx = sx[base + j], qy = sy[base + j];
      kid[j] = ~(unsigned)sid[base + j];
      pxl[j * NCH + t] = qx;
      pyl[j * NCH + t] = qy;
      xmn = fminf(xmn, qx); xmx = fmaxf(xmx, qx);
      ymn = fminf(ymn, qy); ymx = fmaxf(ymx, qy);
      float dx = __fsub_rn(qx, cx), dy = __fsub_rn(qy, cy);
      float nd = __fadd_rn(__fmul_rn(dx, dx), __fmul_rn(dy, dy));
      d[j] = nd;
      unsigned long long kv =
          ((unsigned long long)__float_as_uint(nd) << 32) | kid[j];
      if (kv > best) { best = kv; bx = qx; by = qy; }
    }
    ck[t] = best;
    cp[t] = make_float2(bx, by);
  }
  float cmax = __uint_as_float((unsigned)(ck[t] >> 32));
  __syncthreads();

  for (int i = 1; i < NKEEP; ++i) {
    // ---- single-wave reduce over NCH chunk keys ----
    if (t < 64) {
      unsigned long long bk = 0;
      int sl = 0;
      #pragma unroll
      for (int j = 0; j < NCH / 64; ++j) {
        unsigned long long k = ck[t + j * 64];
        if (k > bk) { bk = k; sl = t + j * 64; }
      }
      // 16-lane row reduce via DPP row_ror
      {
        unsigned hi, lo, ohi, olo; int os;
        hi = (unsigned)(bk >> 32); lo = (unsigned)bk;
        ohi = ror16<1>(hi); olo = ror16<1>(lo); os = (int)ror16<1>((unsigned)sl);
        { unsigned long long ok = ((unsigned long long)ohi << 32) | olo;
          if (ok > bk) { bk = ok; sl = os; } }
        hi = (unsigned)(bk >> 32); lo = (unsigned)bk;
        ohi = ror16<2>(hi); olo = ror16<2>(lo); os = (int)ror16<2>((unsigned)sl);
        { unsigned long long ok = ((unsigned long long)ohi << 32) | olo;
          if (ok > bk) { bk = ok; sl = os; } }
        hi = (unsigned)(bk >> 32); lo = (unsigned)bk;
        ohi = ror16<4>(hi); olo = ror16<4>(lo); os = (int)ror16<4>((unsigned)sl);
        { unsigned long long ok = ((unsigned long long)ohi << 32) | olo;
          if (ok > bk) { bk = ok; sl = os; } }
        hi = (unsigned)(bk >> 32); lo = (unsigned)bk;
        ohi = ror16<8>(hi); olo = ror16<8>(lo); os = (int)ror16<8>((unsigned)sl);
        { unsigned long long ok = ((unsigned long long)ohi << 32) | olo;
          if (ok > bk) { bk = ok; sl = os; } }
      }
      // cross-row: rows' maxima -> uniform winner via readlane
      unsigned hi = (unsigned)(bk >> 32), lo = (unsigned)bk;
      unsigned long long fb = 0; int fs = 0;
      #pragma unroll
      for (int r = 0; r < 4; ++r) {
        unsigned h = (unsigned)__builtin_amdgcn_readlane((int)hi, r * 16);
        unsigned l = (unsigned)__builtin_amdgcn_readlane((int)lo, r * 16);
        int s = __builtin_amdgcn_readlane(sl, r * 16);
        unsigned long long k = ((unsigned long long)h << 32) | l;
        if (k > fb) { fb = k; fs = s; }
      }
      if (t == 0) {
        float2 c = cp[fs];
        perm[i] = (int)(~(unsigned)fb);
        pos_out[2 * i] = c.x; pos_out[2 * i + 1] = c.y;
        bc[0] = c.x; bc[1] = c.y;
      }
    }
    __syncthreads();
    cx = bc[0]; cy = bc[1];

    // ---- pruned chunk update ----
    float mdx = fmaxf(fmaxf(__fsub_rn(xmn, cx), __fsub_rn(cx, xmx)), 0.f);
    float mdy = fmaxf(fmaxf(__fsub_rn(ymn, cy), __fsub_rn(cy, ymx)), 0.f);
    float mb = mdx * mdx + mdy * mdy;
    if (!(mb * 0.99999f > cmax)) {
      unsigned long long best = 0; float bx = 0.f, by = 0.f;
      #pragma unroll
      for (int j = 0; j < CHUNK; ++j) {
        float qx = pxl[j * NCH + t], qy = pyl[j * NCH + t];
        float dx = __fsub_rn(qx, cx), dy = __fsub_rn(qy, cy);
        float nd = __fadd_rn(__fmul_rn(dx, dx), __fmul_rn(dy, dy));
        float dn = fminf(d[j], nd);
        d[j] = dn;
        unsigned long long kv =
            ((unsigned long long)__float_as_uint(dn) << 32) | kid[j];
        if (kv > best) { best = kv; bx = qx; by = qy; }
      }
      ck[t] = best;
      cp[t] = make_float2(bx, by);
      cmax = __uint_as_float((unsigned)(best >> 32));
    }
    __syncthreads();
  }
}

// ---------------- row gather ----------------
__global__ __launch_bounds__(256)
void gather_rows(const float* __restrict__ xin, const int* __restrict__ perm,
                 float* __restrict__ xout, int n) {
  const int wid = threadIdx.x >> 6, lane = threadIdx.x & 63;
  const int i = blockIdx.x * 4 + wid;
  if (i >= n) return;
  const int s = perm[i];
  const float4* r = (const float4*)(xin + (size_t)s * HF);
  float4* o = (float4*)(xout + (size_t)i * HF);
  o[lane] = r[lane];
  o[64 + lane] = r[64 + lane];
}

// ---------------- kNN graph ----------------
template<int NPTS, int K>
__global__ __launch_bounds__(256)
void knn_graph_kernel(const float* __restrict__ pos, int* __restrict__ srcout) {
  __shared__ float sx[NPTS], sy[NPTS], ss[NPTS];
  const int tid = threadIdx.x;
  for (int idx = tid; idx < NPTS; idx += 256) {
    float x = pos[2 * idx], y = pos[2 * idx + 1];
    sx[idx] = x; sy[idx] = y;
    ss[idx] = __fadd_rn(__fmul_rn(x, x), __fmul_rn(y, y));
  }
  __syncthreads();
  const int q = blockIdx.x * 256 + tid;
  const float qx = sx[q], qy = sy[q], qs = ss[q];
  float bd[K]; int bi[K];
  #pragma unroll
  for (int m = 0; m < K; ++m) { bd[m] = 3.4e38f; bi[m] = 0; }
  for (int j = 0; j < NPTS; ++j) {
    if (j == q) continue;
    float dot = __fadd_rn(__fmul_rn(qx, sx[j]), __fmul_rn(qy, sy[j]));
    float d2 = fmaxf(__fsub_rn(__fadd_rn(qs, ss[j]), __fmul_rn(2.0f, dot)), 0.0f);
    if (d2 < bd[K - 1]) {
      bool pr[K];
      #pragma unroll
      for (int m = 0; m < K; ++m) pr[m] = (d2 < bd[m]);
      #pragma unroll
      for (int m = K - 1; m >= 1; --m) {
        bd[m] = pr[m] ? (pr[m - 1] ? bd[m - 1] : d2) : bd[m];
        bi[m] = pr[m] ? (pr[m - 1] ? bi[m - 1] : j) : bi[m];
      }
      if (pr[0]) { bd[0] = d2; bi[0] = j; }
    }
  }
  #pragma unroll
  for (int m = 0; m < K; ++m) srcout[q * K + m] = bi[m];
}

// ---------------- kNN interpolate ----------------
template<int NX, int K>
__global__ __launch_bounds__(256)
void interp_topk(const float* __restrict__ posy, const float* __restrict__ posx,
                 int* __restrict__ oidx, float* __restrict__ ow,
                 float* __restrict__ owsum) {
  __shared__ float sx[NX], sy[NX], ss[NX];
  const int tid = threadIdx.x;
  for (int idx = tid; idx < NX; idx += 256) {
    float x = posx[2 * idx], y = posx[2 * idx + 1];
    sx[idx] = x; sy[idx] = y;
    ss[idx] = __fadd_rn(__fmul_rn(x, x), __fmul_rn(y, y));
  }
  __syncthreads();
  const int q = blockIdx.x * 256 + tid;
  const float qx = posy[2 * q], qy = posy[2 * q + 1];
  const float qs = __fadd_rn(__fmul_rn(qx, qx), __fmul_rn(qy, qy));
  float bd[K]; int bi[K];
  #pragma unroll
  for (int m = 0; m < K; ++m) { bd[m] = 3.4e38f; bi[m] = 0; }
  for (int j = 0; j < NX; ++j) {
    float dot = __fadd_rn(__fmul_rn(qx, sx[j]), __fmul_rn(qy, sy[j]));
    float d2 = fmaxf(__fsub_rn(__fadd_rn(qs, ss[j]), __fmul_rn(2.0f, dot)), 0.0f);
    if (d2 < bd[K - 1]) {
      bool pr[K];
      #pragma unroll
      for (int m = 0; m < K; ++m) pr[m] = (d2 < bd[m]);
      #pragma unroll
      for (int m = K - 1; m >= 1; --m) {
        bd[m] = pr[m] ? (pr[m - 1] ? bd[m - 1] : d2) : bd[m];
        bi[m] = pr[m] ? (pr[m - 1] ? bi[m - 1] : j) : bi[m];
      }
      if (pr[0]) { bd[0] = d2; bi[0] = j; }
    }
  }
  float wsum = 0.f;
  #pragma unroll
  for (int m = 0; m < K; ++m) {
    float w = 1.0f / fmaxf(bd[m], 1e-16f);
    ow[q * K + m] = w;
    oidx[q * K + m] = bi[m];
    wsum = __fadd_rn(wsum, w);
  }
  owsum[q] = wsum;
}

template<int K>
__global__ __launch_bounds__(256)
void interp_combine(const float* __restrict__ xin, const int* __restrict__ idx,
                    const float* __restrict__ w, const float* __restrict__ wsum,
                    float* __restrict__ out, int ny) {
  const int wid = threadIdx.x >> 6, lane = threadIdx.x & 63;
  const int q = blockIdx.x * 4 + wid;
  if (q >= ny) return;
  float4 a0 = {0, 0, 0, 0}, a1 = {0, 0, 0, 0};
  #pragma unroll
  for (int m = 0; m < K; ++m) {
    const int s = idx[q * K + m];
    const float wk = w[q * K + m];
    const float4* r = (const float4*)(xin + (size_t)s * HF);
    a0 = f4fma(wk, r[lane], a0);
    a1 = f4fma(wk, r[64 + lane], a1);
  }
  const float inv = wsum[q];
  a0.x /= inv; a0.y /= inv; a0.z /= inv; a0.w /= inv;
  a1.x /= inv; a1.y /= inv; a1.z /= inv; a1.w /= inv;
  float4* o = (float4*)(out + (size_t)q * HF);
  o[lane] = a0; o[64 + lane] = a1;
}

// ---------------- launcher ----------------
extern "C" void kernel_launch(void* const* d_in, const int* in_sizes, int n_in,
                              void* d_out, int out_size, void* d_ws, size_t ws_size,
                              hipStream_t stream) {
  const float* x    = (const float*)d_in[0];
  const float* pos  = (const float*)d_in[1];
  const int*   ei   = (const int*)d_in[2];
  const float* Wd0  = (const float*)d_in[3];
  const float* bd0  = (const float*)d_in[4];
  const float* Wd1  = (const float*)d_in[5];
  const float* bd1  = (const float*)d_in[6];
  const float* Wu0  = (const float*)d_in[7];
  const float* bu0  = (const float*)d_in[8];
  const float* Wu1  = (const float*)d_in[9];
  const float* bu1  = (const float*)d_in[10];
  const float* Wl   = (const float*)d_in[11];
  const float* bl   = (const float*)d_in[12];
  float* out = (float*)d_out;

  char* ws = (char*)d_ws;
  size_t off = 0;
  auto alloc = [&](size_t bytes) -> char* {
    char* p = ws + off;
    off = (off + bytes + 255) & ~(size_t)255;
    return p;
  };
  float* bufA   = (float*)alloc((size_t)N0 * HF * 4);
  float* bufB   = (float*)alloc((size_t)N0 * HF * 4);
  float* bufC   = (float*)alloc((size_t)N1 * HF * 4);
  float* x2     = (float*)alloc((size_t)N2 * HF * 4);
  int*   offs0  = (int*)alloc((N0 + 1) * 4);
  int*   srcl0  = (int*)alloc(E0C * 4);
  int*   cnt    = (int*)alloc(N0 * 4);
  int*   cursor = (int*)alloc(N0 * 4);
  float* dinv0  = (float*)alloc(N0 * 4);
  int*   perm0  = (int*)alloc(N1 * 4);
  float* pos1   = (float*)alloc(N1 * 2 * 4);
  int*   src1   = (int*)alloc(N1 * 6 * 4);
  int*   perm1  = (int*)alloc(N2 * 4);
  float* pos2   = (float*)alloc(N2 * 2 * 4);
  int*   iidx   = (int*)alloc((size_t)N0 * 6 * 4);
  float* iw     = (float*)alloc((size_t)N0 * 6 * 4);
  float* iwsum  = (float*)alloc(N0 * 4);
  // binning scratch
  float* bsx    = (float*)alloc(N0 * 4);
  float* bsy    = (float*)alloc(N0 * 4);
  int*   bsid   = (int*)alloc(N0 * 4);
  int*   bcid   = (int*)alloc(N0 * 4);
  int*   bhist  = (int*)alloc(1024 * 4);
  int*   bcur   = (int*)alloc(1024 * 4);
  int*   boffs  = (int*)alloc(1025 * 4);

  float* h1   = bufB;
  float* x1f  = bufB + (size_t)N1 * HF;
  float* hu0  = bufB;
  float* xu0f = bufB + (size_t)N1 * HF;

  // level-0 CSR
  hipMemsetAsync(cnt, 0, N0 * 4, stream);
  hipMemsetAsync(cursor, 0, N0 * 4, stream);
  count_deg<<<E0C / 256, 256, 0, stream>>>(ei + E0C, cnt, E0C);
  scan_offsets<<<1, 1024, 0, stream>>>(cnt, offs0, dinv0);
  fill_csr<<<E0C / 256, 256, 0, stream>>>(ei, ei + E0C, offs0, cursor, srcl0, E0C);

  // bin pos (level 0) for FPS0
  hipMemsetAsync(bhist, 0, 1024 * 4, stream);
  hipMemsetAsync(bcur, 0, 1024 * 4, stream);
  bin_hist<<<N0 / 256, 256, 0, stream>>>(pos, bcid, bhist, N0);
  bin_scan<<<1, 1024, 0, stream>>>(bhist, boffs);
  bin_scatter<<<N0 / 256, 256, 0, stream>>>(pos, bcid, boffs, bcur, bsx, bsy, bsid, N0);

  // down 0
  gemm_f32<128, 64, 16><<<dim3(N0 / 128, HF / 64), 256, 0, stream>>>(
      x, Wd0, nullptr, bufA, N0, HF, FIN, 0);
  gcn_agg_csr<<<N0 / 4, 256, 0, stream>>>(bufA, offs0, srcl0, dinv0, bd0, bufB, N0);
  fps_fast<N0, 1024, N1><<<1, 1024, 0, stream>>>(pos, bsx, bsy, bsid, perm0, pos1);
  gather_rows<<<N1 / 4, 256, 0, stream>>>(bufB, perm0, bufC, N1);
  knn_graph_kernel<N1, 6><<<N1 / 256, 256, 0, stream>>>(pos1, src1);

  // bin pos1 for FPS1
  hipMemsetAsync(bhist, 0, 1024 * 4, stream);
  hipMemsetAsync(bcur, 0, 1024 * 4, stream);
  bin_hist<<<N1 / 256, 256, 0, stream>>>(pos1, bcid, bhist, N1);
  bin_scan<<<1, 1024, 0, stream>>>(bhist, boffs);
  bin_scatter<<<N1 / 256, 256, 0, stream>>>(pos1, bcid, boffs, bcur, bsx, bsy, bsid, N1);

  // down 1
  gemm_f32<128, 64, 16><<<dim3(N1 / 128, HF / 64), 256, 0, stream>>>(
      bufC, Wd1, nullptr, h1, N1, HF, HF, 0);
  gcn_agg_knn<6><<<N1 / 4, 256, 0, stream>>>(h1, src1, bd1, x1f, N1);
  fps_fast<N1, 256, N2><<<1, 256, 0, stream>>>(pos1, bsx, bsy, bsid, perm1, pos2);
  gather_rows<<<N2 / 4, 256, 0, stream>>>(x1f, perm1, x2, N2);

  // up 0
  interp_topk<N2, 6><<<N1 / 256, 256, 0, stream>>>(pos1, pos2, iidx, iw, iwsum);
  interp_combine<6><<<N1 / 4, 256, 0, stream>>>(x2, iidx, iw, iwsum, bufC, N1);
  gemm_f32<128, 64, 16><<<dim3(N1 / 128, HF / 64), 256, 0, stream>>>(
      bufC, Wu0, nullptr, hu0, N1, HF, HF, 0);
  gcn_agg_knn<6><<<N1 / 4, 256, 0, stream>>>(hu0, src1, bu0, xu0f, N1);

  // up 1
  interp_topk<N1, 6><<<N0 / 256, 256, 0, stream>>>(pos, pos1, iidx, iw, iwsum);
  interp_combine<6><<<N0 / 4, 256, 0, stream>>>(xu0f, iidx, iw, iwsum, bufA, N0);
  gemm_f32<128, 64, 16><<<dim3(N0 / 128, HF / 64), 256, 0, stream>>>(
      bufA, Wu1, nullptr, bufB, N0, HF, HF, 0);
  gcn_agg_csr<<<N0 / 4, 256, 0, stream>>>(bufB, offs0, srcl0, dinv0, bu1, bufA, N0);

  // final linear
  gemm_f32<128, 64, 16><<<dim3(N0 / 128, HF / 64), 256, 0, stream>>>(
      bufA, Wl, bl, out, N0, HF, HF, 1);
}